// Round 9
// baseline (291.752 us; speedup 1.0000x reference)
//
#include <hip/hip_runtime.h>
#include <hip/hip_bf16.h>
#include <stdint.h>

#define E_ 8
#define H_ 2048
#define I_ 1408
#define T_ 2048
#define K_ 2
#define G_ 128

typedef __bf16 bf16;
typedef bf16 bf16x8 __attribute__((ext_vector_type(8)));
typedef float f32x4 __attribute__((ext_vector_type(4)));

__device__ __forceinline__ uint32_t prm(uint32_t hi, uint32_t lo, uint32_t sel) {
    return __builtin_amdgcn_perm(hi, lo, sel);
}

// Scale-folded dequant tables: bf16(e2m1[m]*s) split into high/low byte LUTs.
struct DequantTab { uint32_t thi0, thi1, tlo0, tlo1; };

__device__ __forceinline__ DequantTab build_tab(float s) {
    union { bf16 h[8]; uint32_t u[4]; } tb;
    tb.h[0] = (bf16)(0.0f);
    tb.h[1] = (bf16)(0.5f * s);
    tb.h[2] = (bf16)(1.0f * s);
    tb.h[3] = (bf16)(1.5f * s);
    tb.h[4] = (bf16)(2.0f * s);
    tb.h[5] = (bf16)(3.0f * s);
    tb.h[6] = (bf16)(4.0f * s);
    tb.h[7] = (bf16)(6.0f * s);
    DequantTab t;
    t.thi0 = prm(tb.u[1], tb.u[0], 0x07050301u);
    t.tlo0 = prm(tb.u[1], tb.u[0], 0x06040200u);
    t.thi1 = prm(tb.u[3], tb.u[2], 0x07050301u);
    t.tlo1 = prm(tb.u[3], tb.u[2], 0x06040200u);
    return t;
}

// 8 fp4 (one u32, k-order) -> 8 scaled bf16 as uint4. ~21 VALU ops.
__device__ __forceinline__ uint4 dequant8t(uint32_t p, const DequantTab& t) {
    const uint32_t pr = p >> 4;
    const uint32_t pe = p  & 0x07070707u;
    const uint32_t po = pr & 0x07070707u;
    const uint32_t He = prm(t.thi1, t.thi0, pe) | ((p  & 0x08080808u) << 4);
    const uint32_t Le = prm(t.tlo1, t.tlo0, pe);
    const uint32_t Ho = prm(t.thi1, t.thi0, po) | ((pr & 0x08080808u) << 4);
    const uint32_t Lo = prm(t.tlo1, t.tlo0, po);
    const uint32_t E01 = prm(He, Le, 0x05010400u);
    const uint32_t E23 = prm(He, Le, 0x07030602u);
    const uint32_t O01 = prm(Ho, Lo, 0x05010400u);
    const uint32_t O23 = prm(Ho, Lo, 0x07030602u);
    return make_uint4(prm(O01, E01, 0x05040100u),
                      prm(O01, E01, 0x07060302u),
                      prm(O23, E23, 0x05040100u),
                      prm(O23, E23, 0x07060302u));
}

// async 16B global -> LDS DMA (wave-uniform-base + lane-linear dest)
__device__ __forceinline__ void gld16(void* lds, const void* g) {
    __builtin_amdgcn_global_load_lds(
        (__attribute__((address_space(1))) void*)g,
        (__attribute__((address_space(3))) void*)lds, 16, 0, 0);
}

// ---------------- routing ----------------
__global__ void route_count(const int* __restrict__ topk_idx, int* __restrict__ counts) {
    int p = blockIdx.x * blockDim.x + threadIdx.x;
    if (p < T_ * K_) atomicAdd(&counts[topk_idx[p]], 1);
}

// tiles of 128 token-pairs
__global__ void route_scan(const int* __restrict__ counts, int* __restrict__ offsets,
                           int* __restrict__ tmap) {
    if (threadIdx.x == 0) {
        int acc = 0, ti = 0;
        for (int e = 0; e < E_; e++) {
            offsets[e] = acc;
            int nt = (counts[e] + 127) >> 7;
            for (int j = 0; j < nt; j++) tmap[ti++] = (e << 16) | j;
            acc += counts[e];
        }
        offsets[E_] = acc;
        for (; ti < 64; ti++) tmap[ti] = -1;
    }
}

__global__ void route_fill(const int* __restrict__ topk_idx, const float* __restrict__ topk_w,
                           int* __restrict__ cursors, const int* __restrict__ offsets,
                           int* __restrict__ tok, float* __restrict__ wgt,
                           int* __restrict__ inv) {
    int p = blockIdx.x * blockDim.x + threadIdx.x;
    if (p < T_ * K_) {
        int e = topk_idx[p];
        int slot = atomicAdd(&cursors[e], 1);
        int idx = offsets[e] + slot;
        tok[idx] = p / K_;
        wgt[idx] = topk_w[p];
        inv[p] = idx;
    }
}

// x f32 -> bf16
__global__ __launch_bounds__(256)
void xcast_kernel(const float* __restrict__ x, uint4* __restrict__ xb) {
    const int i = blockIdx.x * 256 + threadIdx.x;
    const float4 a = ((const float4*)x)[i * 2];
    const float4 b = ((const float4*)x)[i * 2 + 1];
    union { uint4 u; bf16 h[8]; } r;
    r.h[0] = (bf16)a.x; r.h[1] = (bf16)a.y; r.h[2] = (bf16)a.z; r.h[3] = (bf16)a.w;
    r.h[4] = (bf16)b.x; r.h[5] = (bf16)b.y; r.h[6] = (bf16)b.z; r.h[7] = (bf16)b.w;
    xb[i] = r.u;
}

// ---------------- GEMM1: 128tok x 64i, BK=64, pipelined ----------------
// x double-buffered (issued after barrier1, overlaps MFMA); weights
// single-buffered (dequant in stage window). Swizzled LDS (0 conflicts).
__global__ __launch_bounds__(256, 3)
void gemm1q_kernel(const bf16* __restrict__ xb,
                   const uint32_t* __restrict__ gate_packed,
                   const float* __restrict__ gate_scales,
                   const uint32_t* __restrict__ up_packed,
                   const float* __restrict__ up_scales,
                   const int* __restrict__ offsets,
                   const int* __restrict__ tmap,
                   const int* __restrict__ tok, bf16* __restrict__ h_buf)
{
    const int tm = tmap[blockIdx.x];
    if (tm < 0) return;
    const int e = tm >> 16, ty = tm & 0xffff;       // 128-token tile
    const int row0 = offsets[e];
    const int cnt = offsets[e + 1] - row0;
    const int itile = blockIdx.y;                    // 64 i-cols

    __shared__ __align__(16) bf16 xs[2][128][64];    // 2 x 16 KB
    __shared__ __align__(16) bf16 wgs[64][64];       // 8 KB
    __shared__ __align__(16) bf16 wus[64][64];       // 8 KB
    __shared__ int toks[128];

    const int tid = threadIdx.x;
    if (tid < 128) {
        int r = ty * 128 + tid;
        toks[tid] = tok[row0 + ((r < cnt) ? r : (cnt - 1))];
    }
    __syncthreads();

    // --- x staging: 4 swizzled 16B chunks per thread per step ---
    const bf16* xsrc[4];
    int xf[4];
#pragma unroll
    for (int i = 0; i < 4; i++) {
        const int f = i * 256 + tid;        // flat chunk id (128 rows x 8 chunks)
        const int r = f >> 3, c = f & 7;
        xf[i] = f;
        xsrc[i] = xb + (size_t)toks[r] * H_ + ((c ^ (r & 7)) * 8);
    }

    // --- weight staging: each thread 1 uint4 (4 u32) of one matrix row ---
    const int mat  = tid >> 7;           // 0 = gate, 1 = up
    const int id   = tid & 127;
    const int wrow = id >> 1;            // 0..63
    const int quad = id & 1;             // chunk group
    const int irow = itile * 64 + wrow;
    const uint32_t* wp = (mat ? up_packed : gate_packed)
        + (size_t)e * I_ * (H_ / 8) + (size_t)irow * (H_ / 8) + quad * 4;
    const float* ws_row = (mat ? up_scales : gate_scales)
        + (size_t)e * (H_ / G_) * I_ + irow;
    bf16 (* const wdst)[64] = mat ? wus : wgs;
    const int cb = quad * 4, rs = wrow & 7;

    const int wave = tid >> 6, lane = tid & 63;
    const int wy = wave >> 1, wx = wave & 1;
    const int lrow = lane & 15, kq = lane >> 4;

    f32x4 accg[4][2] = {};
    f32x4 accu[4][2] = {};

    // prologue: stage step 0
    uint4 pw = *(const uint4*)wp;
    DequantTab tw = build_tab(ws_row[0]);
#pragma unroll
    for (int i = 0; i < 4; i++)
        gld16((char*)&xs[0][0][0] + xf[i] * 16, xsrc[i]);
    {
        uint4 d0 = dequant8t(pw.x, tw), d1 = dequant8t(pw.y, tw);
        uint4 d2 = dequant8t(pw.z, tw), d3 = dequant8t(pw.w, tw);
        *(uint4*)&wdst[wrow][((cb + 0) ^ rs) * 8] = d0;
        *(uint4*)&wdst[wrow][((cb + 1) ^ rs) * 8] = d1;
        *(uint4*)&wdst[wrow][((cb + 2) ^ rs) * 8] = d2;
        *(uint4*)&wdst[wrow][((cb + 3) ^ rs) * 8] = d3;
    }
    __syncthreads();                                   // barrier1(0)

    for (int ks = 0; ks < 32; ks++) {                  // K = 32 x BK64
        const int b = ks & 1;
        const bool hasn = (ks < 31);
        uint4 pw_n;
        // compute window: issue next-step loads first (overlap MFMA)
        if (hasn) {
            pw_n = *(const uint4*)(wp + (ks + 1) * 8);
#pragma unroll
            for (int i = 0; i < 4; i++)
                gld16((char*)&xs[b ^ 1][0][0] + xf[i] * 16, xsrc[i] + (ks + 1) * 64);
        }
#pragma unroll
        for (int kh = 0; kh < 2; kh++) {
            bf16x8 a[4], bg[2], bu[2];
#pragma unroll
            for (int mi = 0; mi < 4; mi++) {
                const int ra = wy * 64 + mi * 16 + lrow;
                a[mi] = *(const bf16x8*)&xs[b][ra][((kh * 4 + kq) ^ (ra & 7)) * 8];
            }
#pragma unroll
            for (int ni = 0; ni < 2; ni++) {
                const int rb = wx * 32 + ni * 16 + lrow;
                const int cc = ((kh * 4 + kq) ^ (rb & 7)) * 8;
                bg[ni] = *(const bf16x8*)&wgs[rb][cc];
                bu[ni] = *(const bf16x8*)&wus[rb][cc];
            }
#pragma unroll
            for (int mi = 0; mi < 4; mi++)
#pragma unroll
                for (int ni = 0; ni < 2; ni++) {
                    accg[mi][ni] = __builtin_amdgcn_mfma_f32_16x16x32_bf16(a[mi], bg[ni], accg[mi][ni], 0, 0, 0);
                    accu[mi][ni] = __builtin_amdgcn_mfma_f32_16x16x32_bf16(a[mi], bu[ni], accu[mi][ni], 0, 0, 0);
                }
        }
        __syncthreads();                               // barrier2: w reads done
        if (hasn) {
            if (ks & 1) tw = build_tab(ws_row[((ks + 1) >> 1) * I_]);
            uint4 d0 = dequant8t(pw_n.x, tw), d1 = dequant8t(pw_n.y, tw);
            uint4 d2 = dequant8t(pw_n.z, tw), d3 = dequant8t(pw_n.w, tw);
            *(uint4*)&wdst[wrow][((cb + 0) ^ rs) * 8] = d0;
            *(uint4*)&wdst[wrow][((cb + 1) ^ rs) * 8] = d1;
            *(uint4*)&wdst[wrow][((cb + 2) ^ rs) * 8] = d2;
            *(uint4*)&wdst[wrow][((cb + 3) ^ rs) * 8] = d3;
            __syncthreads();                           // barrier1(next)
        }
    }

    // epilogue: h = silu(g)*u. C layout: col=lane&15, row=(lane>>4)*4+r
#pragma unroll
    for (int mi = 0; mi < 4; mi++)
#pragma unroll
        for (int ni = 0; ni < 2; ni++) {
            const int icol = itile * 64 + wx * 32 + ni * 16 + lrow;
#pragma unroll
            for (int r = 0; r < 4; r++) {
                const int grow = ty * 128 + wy * 64 + mi * 16 + kq * 4 + r;
                if (grow < cnt) {
                    const float gv = accg[mi][ni][r];
                    const float hv = gv / (1.f + __expf(-gv)) * accu[mi][ni][r];
                    h_buf[(size_t)(row0 + grow) * I_ + icol] = (bf16)hv;
                }
            }
        }
}

// ---------------- GEMM2: 128tok x 128h, BK=64, pipelined -> yp ----------------
__global__ __launch_bounds__(256, 3)
void gemm2q_kernel(const bf16* __restrict__ h_buf,
                   const uint32_t* __restrict__ down_packed,
                   const float* __restrict__ down_scales,
                   const int* __restrict__ offsets,
                   const int* __restrict__ tmap,
                   const float* __restrict__ wgt, float* __restrict__ yp)
{
    const int tm = tmap[blockIdx.x];
    if (tm < 0) return;
    const int e = tm >> 16, ty = tm & 0xffff;
    const int row0 = offsets[e];
    const int cnt = offsets[e + 1] - row0;
    const int htile = blockIdx.y;                    // 128 h-cols

    __shared__ __align__(16) bf16 hs[2][128][64];    // 2 x 16 KB
    __shared__ __align__(16) bf16 wds[128][64];      // 16 KB

    const int tid = threadIdx.x;

    // --- h staging: 4 swizzled chunks per thread per step ---
    const bf16* hsrc[4];
    int hf[4];
#pragma unroll
    for (int i = 0; i < 4; i++) {
        const int f = i * 256 + tid;
        const int r = f >> 3, c = f & 7;
        int g = ty * 128 + r;  g = (g < cnt) ? g : (cnt - 1);
        hf[i] = f;
        hsrc[i] = h_buf + (size_t)(row0 + g) * I_ + ((c ^ (r & 7)) * 8);
    }

    // --- weight staging: 128 rows x 8 u32 -> 1 uint4/thread/step ---
    const int wrow = tid >> 1;           // 0..127
    const int quad = tid & 1;
    const int hrow = htile * 128 + wrow;
    const uint32_t* dp = down_packed + (size_t)e * H_ * (I_ / 8) + (size_t)hrow * (I_ / 8) + quad * 4;
    const float* ds_row = down_scales + (size_t)e * (I_ / G_) * H_ + hrow;
    const int cb = quad * 4, rs = wrow & 7;

    const int wave = tid >> 6, lane = tid & 63;
    const int wy = wave >> 1, wx = wave & 1;
    const int lrow = lane & 15, kq = lane >> 4;

    f32x4 acc[4][4] = {};

    // prologue
    uint4 pw = *(const uint4*)dp;
    DequantTab tw = build_tab(ds_row[0]);
#pragma unroll
    for (int i = 0; i < 4; i++)
        gld16((char*)&hs[0][0][0] + hf[i] * 16, hsrc[i]);
    {
        uint4 d0 = dequant8t(pw.x, tw), d1 = dequant8t(pw.y, tw);
        uint4 d2 = dequant8t(pw.z, tw), d3 = dequant8t(pw.w, tw);
        *(uint4*)&wds[wrow][((cb + 0) ^ rs) * 8] = d0;
        *(uint4*)&wds[wrow][((cb + 1) ^ rs) * 8] = d1;
        *(uint4*)&wds[wrow][((cb + 2) ^ rs) * 8] = d2;
        *(uint4*)&wds[wrow][((cb + 3) ^ rs) * 8] = d3;
    }
    __syncthreads();

    for (int ks = 0; ks < I_ / 64; ks++) {           // 22 steps
        const int b = ks & 1;
        const bool hasn = (ks < I_ / 64 - 1);
        uint4 pw_n;
        if (hasn) {
            pw_n = *(const uint4*)(dp + (ks + 1) * 8);
#pragma unroll
            for (int i = 0; i < 4; i++)
                gld16((char*)&hs[b ^ 1][0][0] + hf[i] * 16, hsrc[i] + (ks + 1) * 64);
        }
#pragma unroll
        for (int kh = 0; kh < 2; kh++) {
            bf16x8 a[4], bb[4];
#pragma unroll
            for (int mi = 0; mi < 4; mi++) {
                const int ra = wy * 64 + mi * 16 + lrow;
                a[mi] = *(const bf16x8*)&hs[b][ra][((kh * 4 + kq) ^ (ra & 7)) * 8];
            }
#pragma unroll
            for (int ni = 0; ni < 4; ni++) {
                const int rb = wx * 64 + ni * 16 + lrow;
                bb[ni] = *(const bf16x8*)&wds[rb][((kh * 4 + kq) ^ (rb & 7)) * 8];
            }
#pragma unroll
            for (int mi = 0; mi < 4; mi++)
#pragma unroll
                for (int ni = 0; ni < 4; ni++)
                    acc[mi][ni] = __builtin_amdgcn_mfma_f32_16x16x32_bf16(a[mi], bb[ni], acc[mi][ni], 0, 0, 0);
        }
        __syncthreads();
        if (hasn) {
            if (ks & 1) tw = build_tab(ds_row[((ks + 1) >> 1) * H_]);
            uint4 d0 = dequant8t(pw_n.x, tw), d1 = dequant8t(pw_n.y, tw);
            uint4 d2 = dequant8t(pw_n.z, tw), d3 = dequant8t(pw_n.w, tw);
            *(uint4*)&wds[wrow][((cb + 0) ^ rs) * 8] = d0;
            *(uint4*)&wds[wrow][((cb + 1) ^ rs) * 8] = d1;
            *(uint4*)&wds[wrow][((cb + 2) ^ rs) * 8] = d2;
            *(uint4*)&wds[wrow][((cb + 3) ^ rs) * 8] = d3;
            __syncthreads();
        }
    }

    // epilogue: plain stores of wgt-scaled partials
#pragma unroll
    for (int mi = 0; mi < 4; mi++)
#pragma unroll
        for (int r = 0; r < 4; r++) {
            const int grow = ty * 128 + wy * 64 + mi * 16 + kq * 4 + r;
            if (grow < cnt) {
                const float w = wgt[row0 + grow];
#pragma unroll
                for (int ni = 0; ni < 4; ni++) {
                    const int col = htile * 128 + wx * 64 + ni * 16 + lrow;
                    yp[(size_t)(row0 + grow) * H_ + col] = acc[mi][ni][r] * w;
                }
            }
        }
}

// ---------------- combine: out[t] = sum over K pairs ----------------
__global__ __launch_bounds__(256)
void combine_kernel(const float* __restrict__ yp, const int* __restrict__ inv,
                    float* __restrict__ out) {
    const int idx = blockIdx.x * 256 + threadIdx.x;   // T_*H_/4 units
    const int t = idx >> 9;                            // / (H_/4 = 512)
    const int c = idx & 511;
    const float4 a = ((const float4*)yp)[(size_t)inv[t * 2] * (H_ / 4) + c];
    const float4 b = ((const float4*)yp)[(size_t)inv[t * 2 + 1] * (H_ / 4) + c];
    float4 o;
    o.x = a.x + b.x; o.y = a.y + b.y; o.z = a.z + b.z; o.w = a.w + b.w;
    ((float4*)out)[idx] = o;
}

extern "C" void kernel_launch(void* const* d_in, const int* in_sizes, int n_in,
                              void* d_out, int out_size, void* d_ws, size_t ws_size,
                              hipStream_t stream) {
    const float* x = (const float*)d_in[0];
    const uint32_t* gate_packed = (const uint32_t*)d_in[1];
    const float* gate_scales = (const float*)d_in[2];
    const uint32_t* up_packed = (const uint32_t*)d_in[3];
    const float* up_scales = (const float*)d_in[4];
    const uint32_t* down_packed = (const uint32_t*)d_in[5];
    const float* down_scales = (const float*)d_in[6];
    const int* topk_idx = (const int*)d_in[7];
    const float* topk_w = (const float*)d_in[8];
    float* out = (float*)d_out;

    // workspace layout (bytes)
    char* ws = (char*)d_ws;
    int* counts  = (int*)ws;              // 32
    int* cursors = (int*)(ws + 32);       // 32
    int* offsets = (int*)(ws + 64);       // 64
    int* tmap    = (int*)(ws + 128);      // 512 (128 ints, 64 used)
    int* tok     = (int*)(ws + 640);      // 16384
    float* wgt   = (float*)(ws + 17024);  // 16384
    int* inv     = (int*)(ws + 33408);    // 16384
    bf16* h_buf  = (bf16*)(ws + 49792);   // 11,534,336
    bf16* xb     = (bf16*)(ws + 49792 + 11534336ull);                 // 8,388,608
    float* yp    = (float*)(ws + 49792 + 11534336ull + 8388608ull);   // 33,554,432

    hipMemsetAsync(d_ws, 0, 1024, stream);

    route_count<<<(T_ * K_ + 255) / 256, 256, 0, stream>>>(topk_idx, counts);
    route_scan<<<1, 64, 0, stream>>>(counts, offsets, tmap);
    route_fill<<<(T_ * K_ + 255) / 256, 256, 0, stream>>>(topk_idx, topk_w, cursors, offsets,
                                                          tok, wgt, inv);
    xcast_kernel<<<T_ * H_ / 8 / 256, 256, 0, stream>>>(x, (uint4*)xb);

    dim3 g1(40, I_ / 64);    // x = 128-token tile, y = itile
    gemm1q_kernel<<<g1, 256, 0, stream>>>(xb, gate_packed, gate_scales, up_packed, up_scales,
                                          offsets, tmap, tok, h_buf);
    dim3 g2(40, H_ / 128);   // x = 128-token tile, y = htile
    gemm2q_kernel<<<g2, 256, 0, stream>>>(h_buf, down_packed, down_scales,
                                          offsets, tmap, wgt, yp);
    combine_kernel<<<T_ * H_ / 4 / 256, 256, 0, stream>>>(yp, inv, out);
}